// Round 3
// baseline (40320.483 us; speedup 1.0000x reference)
//
#include <hip/hip_runtime.h>
#include <hip/hip_cooperative_groups.h>

namespace cg = cooperative_groups;

#define T_DIM 512
#define B_DIM 64
#define H_DIM 1024
#define RPAD 36   // max chunk rows 35, padded to 9 float4-quads (odd quad count -> uniform banks)

// ws layout (floats):
//   P    [256][64 b][64 j][4 s]  per-chunk partials (16 MB), XCD-local by construction
//   hbuf [2][B][H]               hidden ping-pong
//   pmax [T][B][16]              per-jb label maxes

__global__ __launch_bounds__(256) void init_h(const float* __restrict__ h0, float* __restrict__ hbuf)
{
    const int i = blockIdx.x * 256 + threadIdx.x;
    if (i < B_DIM * H_DIM) hbuf[i] = h0[i];
}

// 256 WGs x 512 threads, cooperative. Chunk schedule: per j-block jb (64 cols),
// k-range [64*jb, 1024) split into NJB[jb] chunks (<=35 rows). NJB[jb]+NJB[15-jb]==32,
// so XCD x owns families (x, 15-x): blockIdx = slot*8+xcd keeps each jb family on one XCD.
__global__ __launch_bounds__(512, 1) void gru_main(
    const float* __restrict__ x,
    const float* __restrict__ Wir, const float* __restrict__ Whr,
    const float* __restrict__ Wiz, const float* __restrict__ Whz,
    const float* __restrict__ Win, const float* __restrict__ Whn,
    const float* __restrict__ bir, const float* __restrict__ bhr,
    const float* __restrict__ biz, const float* __restrict__ bhz,
    const float* __restrict__ bin_, const float* __restrict__ bhn,
    const float* __restrict__ Wout, const float* __restrict__ bout,
    float* __restrict__ hbuf, float* __restrict__ P, float* __restrict__ pmax)
{
    constexpr int NJB[16] = {30,28,26,24,23,21,19,17,15,13,11,9,8,6,4,2};
    constexpr int C0[16]  = {0,30,58,84,108,131,152,171,188,203,216,227,236,244,250,254};

    __shared__ float w_lds[6 * 64 * RPAD];  // [g][j-lane][r] 55,296 B
    __shared__ float xs[64 * RPAD];         // [b][r] 9,216 B
    __shared__ float hs[64 * RPAD];         // [b][r] 9,216 B

    cg::grid_group grid = cg::this_grid();

    const int tid  = threadIdx.x;
    const int lane = tid & 63;
    const int ww   = tid >> 6;

    // XCD-local chunk assignment (blockIdx round-robins XCDs by &7; perf-only heuristic)
    const int xcd  = blockIdx.x & 7;
    const int slot = blockIdx.x >> 3;
    const bool first = (slot < NJB[xcd]);
    const int jb   = first ? xcd : (15 - xcd);
    const int i_in = first ? slot : (slot - NJB[xcd]);
    const int njb  = NJB[jb];
    const int Cb   = C0[jb];
    const int cid  = Cb + i_in;

    const int j0   = jb << 6;
    const int Kjb  = H_DIM - j0;
    const int base = Kjb / njb, rem = Kjb % njb;
    const int ks   = j0 + i_in * base + (i_in < rem ? i_in : rem);
    const int kr   = base + (i_in < rem ? 1 : 0);   // <= 35

    // zero LDS (weight pad rows + x/h pad rows must be 0, not garbage)
    for (int i = tid; i < 6 * 64 * RPAD; i += 512) w_lds[i] = 0.0f;
    for (int i = tid; i < 64 * RPAD; i += 512) { xs[i] = 0.0f; hs[i] = 0.0f; }
    __syncthreads();

    // load masked weights once: w_lds[(g*64+lane)*RPAD + r] = (k>=j) ? W_g[k][j0+lane] : 0
    {
        const float* Wsrc[6] = {Wir, Wiz, Win, Whr, Whz, Whn};
        for (int g = 0; g < 6; ++g) {
            const float* src = Wsrc[g] + j0 + lane;
            float* dst = &w_lds[(g * 64 + lane) * RPAD];
            for (int r = ww; r < kr; r += 8) {
                const int k = ks + r;
                float v = src[(size_t)k * H_DIM];
                if (k - j0 < lane) v = 0.0f;
                dst[r] = v;
            }
        }
    }

    // phase-B per-thread constants (column j fixed for this WG)
    const int jB = j0 + lane;
    const float c_bir = bir[jB], c_bhr = bhr[jB];
    const float c_biz = biz[jB], c_bhz = bhz[jB];
    const float c_bin = bin_[jB], c_bhn = bhn[jB];
    const float c_wo = Wout[jB], bo = bout[0];
    const int bs = (i_in * B_DIM) / njb;
    const int be = ((i_in + 1) * B_DIM) / njb;

    float4* P4w = (float4*)P + ((size_t)cid * 64 + 8 * ww) * 64 + lane;
    const float4* P4 = (const float4*)P;

    for (int t = 0; t < T_DIM; ++t) {
        const float* hid  = hbuf + (size_t)(t & 1) * (B_DIM * H_DIM);
        float*       hidn = hbuf + (size_t)((t + 1) & 1) * (B_DIM * H_DIM);
        const float* xt   = x + (size_t)t * (B_DIM * H_DIM);

        // ---- stage x,h k-slices: xs[b][r], hs[b][r] for r < kr ----
        for (int b = ww; b < B_DIM; b += 8) {
            if (lane < kr) {
                xs[b * RPAD + lane] = xt[(size_t)b * H_DIM + ks + lane];
                hs[b * RPAD + lane] = hid[(size_t)b * H_DIM + ks + lane];
            }
        }
        __syncthreads();

        // ---- phase A: per-thread acc[8 b][4 sums] over the chunk's k rows ----
        float4 acc[8];
        #pragma unroll
        for (int i = 0; i < 8; ++i) acc[i] = make_float4(0.f, 0.f, 0.f, 0.f);

        #pragma unroll 3
        for (int q = 0; q < 9; ++q) {
            const int ro = 4 * q;
            const float4 w0 = *(const float4*)&w_lds[(0 * 64 + lane) * RPAD + ro]; // ir
            const float4 w1 = *(const float4*)&w_lds[(1 * 64 + lane) * RPAD + ro]; // iz
            const float4 w2 = *(const float4*)&w_lds[(2 * 64 + lane) * RPAD + ro]; // in
            const float4 w3 = *(const float4*)&w_lds[(3 * 64 + lane) * RPAD + ro]; // hr
            const float4 w4 = *(const float4*)&w_lds[(4 * 64 + lane) * RPAD + ro]; // hz
            const float4 w5 = *(const float4*)&w_lds[(5 * 64 + lane) * RPAD + ro]; // hn
            #pragma unroll
            for (int i = 0; i < 8; ++i) {
                const int b = 8 * ww + i;
                const float4 xv = *(const float4*)&xs[b * RPAD + ro]; // wave-uniform broadcast
                const float4 hv = *(const float4*)&hs[b * RPAD + ro];
#define ACC(c) \
                acc[i].x = fmaf(xv.c, w0.c, fmaf(hv.c, w3.c, acc[i].x)); \
                acc[i].y = fmaf(xv.c, w1.c, fmaf(hv.c, w4.c, acc[i].y)); \
                acc[i].z = fmaf(xv.c, w2.c, acc[i].z); \
                acc[i].w = fmaf(hv.c, w5.c, acc[i].w);
                ACC(x) ACC(y) ACC(z) ACC(w)
#undef ACC
            }
        }

        // ---- write partials: P[cid][b][j][4], 1KB per wave-store ----
        #pragma unroll
        for (int i = 0; i < 8; ++i) P4w[(size_t)i * 64] = acc[i];

        grid.sync();   // all partials of step t visible

        // ---- phase B: reduce this jb's chunks for b-slice [bs,be), gates, label ----
        for (int b = bs + ww; b < be; b += 8) {
            float4 s = make_float4(0.f, 0.f, 0.f, 0.f);
            const float4* pc = P4 + ((size_t)Cb * 64 + b) * 64 + lane;
            for (int c = 0; c < njb; ++c) {
                const float4 v = pc[(size_t)c * 64 * 64];
                s.x += v.x; s.y += v.y; s.z += v.z; s.w += v.w;
            }
            const float xv = xt[(size_t)b * H_DIM + jB];
            const float hv = hid[(size_t)b * H_DIM + jB];
            const float rp = s.x + c_bir * xv + c_bhr;
            const float zp = s.y + c_biz * xv + c_bhz;
            const float r  = 1.0f / (1.0f + expf(-rp));
            const float z  = 1.0f / (1.0f + expf(-zp));
            const float np = s.z + c_bin * xv + r * (s.w + c_bhn);
            const float n  = tanhf(np);
            const float hnew = hv * z + (1.0f - z) * n;
            hidn[(size_t)b * H_DIM + jB] = hnew;
            float lab = (1.0f / (1.0f + expf(-(hnew * c_wo + bo)))) * xv;
            #pragma unroll
            for (int off = 32; off; off >>= 1)
                lab = fmaxf(lab, __shfl_xor(lab, off));
            if (lane == 0) pmax[((size_t)t * B_DIM + b) * 16 + jb] = lab;
        }

        grid.sync();   // h(t+1) visible; P free for overwrite
    }
}

__global__ __launch_bounds__(256) void finalize(const float* __restrict__ pmax, int* __restrict__ out)
{
    const int i = blockIdx.x * 256 + threadIdx.x; // 0..T*B-1
    if (i >= T_DIM * B_DIM) return;
    const float4* pm = (const float4*)(pmax + (size_t)i * 16);
    float m = -3.4e38f;
    #pragma unroll
    for (int q = 0; q < 4; ++q) {
        const float4 v = pm[q];
        m = fmaxf(m, fmaxf(fmaxf(v.x, v.y), fmaxf(v.z, v.w)));
    }
    out[i] = (m >= 0.5f) ? 1 : -1;
}

extern "C" void kernel_launch(void* const* d_in, const int* in_sizes, int n_in,
                              void* d_out, int out_size, void* d_ws, size_t ws_size,
                              hipStream_t stream)
{
    const float* x    = (const float*)d_in[0];
    const float* h0   = (const float*)d_in[1];
    const float* W_ir = (const float*)d_in[2];
    const float* W_hr = (const float*)d_in[3];
    const float* W_iz = (const float*)d_in[4];
    const float* W_hz = (const float*)d_in[5];
    const float* W_in = (const float*)d_in[6];
    const float* W_hn = (const float*)d_in[7];
    const float* b_ir = (const float*)d_in[8];
    const float* b_hr = (const float*)d_in[9];
    const float* b_iz = (const float*)d_in[10];
    const float* b_hz = (const float*)d_in[11];
    const float* b_in = (const float*)d_in[12];
    const float* b_hn = (const float*)d_in[13];
    const float* W_out = (const float*)d_in[14];
    const float* b_out = (const float*)d_in[15];

    float* ws   = (float*)d_ws;
    float* P    = ws;                                   // 256*64*64*4 = 4,194,304 floats
    float* hbuf = P + (size_t)256 * 64 * 64 * 4;        // 2*B*H
    float* pmax = hbuf + (size_t)2 * B_DIM * H_DIM;     // T*B*16

    init_h<<<dim3(256), 256, 0, stream>>>(h0, hbuf);

    void* args[] = {(void*)&x,
                    (void*)&W_ir, (void*)&W_hr, (void*)&W_iz, (void*)&W_hz,
                    (void*)&W_in, (void*)&W_hn,
                    (void*)&b_ir, (void*)&b_hr, (void*)&b_iz, (void*)&b_hz,
                    (void*)&b_in, (void*)&b_hn, (void*)&W_out, (void*)&b_out,
                    (void*)&hbuf, (void*)&P, (void*)&pmax};
    hipLaunchCooperativeKernel((const void*)gru_main, dim3(256), dim3(512), args, 0, stream);

    finalize<<<dim3(T_DIM * B_DIM / 256), 256, 0, stream>>>(pmax, (int*)d_out);
}

// Round 4
// 18704.935 us; speedup vs baseline: 2.1556x; 2.1556x over previous
//
#include <hip/hip_runtime.h>
#include <hip/hip_cooperative_groups.h>

namespace cg = cooperative_groups;

#define T_DIM 512
#define B_DIM 64
#define H_DIM 1024
#define NQ 256          // k-quads per gate (H/4)

// ws layout (floats):
//   Wv   [6][NQ][H][4]  masked, k-quad-interleaved weights:
//                       Wv[g][kq][j][u] = (4kq+u >= j) ? W_g[4kq+u][j] : 0
//   hbuf [2][B][H]      hidden ping-pong
//   pmax [T][B][16]     per-jb label maxes

// ---------------- prep: mask + k-quad interleave ----------------
__global__ __launch_bounds__(256) void prep_interleave(
    const float* __restrict__ Wir, const float* __restrict__ Wiz, const float* __restrict__ Win,
    const float* __restrict__ Whr, const float* __restrict__ Whz, const float* __restrict__ Whn,
    float* __restrict__ Wv)
{
    const float* srcs[6] = {Wir, Wiz, Win, Whr, Whz, Whn};
    const int kq = blockIdx.x;                    // 0..255
    const int j  = blockIdx.y * 256 + threadIdx.x;
    const int g  = blockIdx.z;
    const float* src = srcs[g];
    float tmp[4];
    #pragma unroll
    for (int u = 0; u < 4; ++u) {
        const int k = 4 * kq + u;
        const float w = src[(size_t)k * H_DIM + j];   // lanes j: coalesced
        tmp[u] = (k >= j) ? w : 0.0f;                 // tril mask
    }
    float4* dst = (float4*)Wv + ((size_t)g * NQ + kq) * H_DIM + j;
    *dst = make_float4(tmp[0], tmp[1], tmp[2], tmp[3]);
}

__global__ __launch_bounds__(256) void init_h(const float* __restrict__ h0, float* __restrict__ hbuf)
{
    const int i = blockIdx.x * 256 + threadIdx.x;
    if (i < B_DIM * H_DIM) hbuf[i] = h0[i];
}

// ---------------- main: 128 WGs x 1024 threads, 1 grid.sync/step ----------------
// WG = (pair p = blockIdx&7, batch rows b0..b0+3). Pair p owns column blocks {p, 15-p}
// (uniform 1088 k-rows). 16 waves split the k-range; LDS reduction; waves 0-3 epilogue.
__global__ __launch_bounds__(1024, 4) void gru_main(
    const float* __restrict__ x,      // [T,B,H]
    const float* __restrict__ Wv,     // [6,NQ,H,4]
    const float* __restrict__ bir, const float* __restrict__ bhr,
    const float* __restrict__ biz, const float* __restrict__ bhz,
    const float* __restrict__ bin_, const float* __restrict__ bhn,
    const float* __restrict__ Wout, const float* __restrict__ bout,
    float* __restrict__ hbuf,         // [2,B,H]
    float* __restrict__ pmax)         // [T,B,16]
{
    cg::grid_group grid = cg::this_grid();

    __shared__ float4 sxh[NQ][9];     // [kq_rel][c] c<4: x rows b0..b0+3, c>=4: h rows; [8]=pad
    __shared__ float4 red[16][4][64]; // [wave][b][j-lane] partials (r,z,ni,nh)

    const int tid  = threadIdx.x;
    const int lane = tid & 63;
    const int ww   = tid >> 6;        // 0..15
    const int p    = blockIdx.x & 7;  // pair (also XCD round-robin)
    const int bg   = blockIdx.x >> 3; // 0..15
    const int b0   = bg * 4;

    const int kq0  = 16 * p;          // staged quad origin (min k over both blocks)
    const int nq   = NQ - kq0;        // staged quad count

    const float bo = bout[0];

    const float4* Wv4 = (const float4*)Wv;

    for (int t = 0; t < T_DIM; ++t) {
        const float* hid  = hbuf + (size_t)(t & 1) * (B_DIM * H_DIM);
        float*       hidn = hbuf + (size_t)((t + 1) & 1) * (B_DIM * H_DIM);
        const float* xt   = x + (size_t)t * (B_DIM * H_DIM);

        // ---- stage x,h (4 rows each) into transposed quad layout ----
        {
            const int c = tid >> 7;                       // 0..7
            const int b = b0 + (c & 3);
            const float* src = (c < 4 ? xt : hid) + (size_t)b * H_DIM;
            #pragma unroll
            for (int r = 0; r < 2; ++r) {
                const int kq = (tid & 127) + (r << 7);    // consecutive lanes -> consecutive kq
                if (kq < nq)
                    sxh[kq][c] = *(const float4*)(src + 4 * (kq0 + kq));
            }
        }
        __syncthreads();

        for (int blk = 0; blk < 2; ++blk) {
            const int jb  = blk ? (15 - p) : p;
            const int j0  = jb << 6;
            const int j   = j0 + lane;
            const int qpw = 16 - jb;                      // quads per wave
            const int qs  = (jb << 4) + ww * qpw;         // global quad start

            // 6 per-gate base pointers at column j
            const float4* w0p = Wv4 + (size_t)0 * NQ * H_DIM + j; // ir
            const float4* w1p = Wv4 + (size_t)1 * NQ * H_DIM + j; // iz
            const float4* w2p = Wv4 + (size_t)2 * NQ * H_DIM + j; // in
            const float4* w3p = Wv4 + (size_t)3 * NQ * H_DIM + j; // hr
            const float4* w4p = Wv4 + (size_t)4 * NQ * H_DIM + j; // hz
            const float4* w5p = Wv4 + (size_t)5 * NQ * H_DIM + j; // hn

            float4 acc[4];
            #pragma unroll
            for (int i = 0; i < 4; ++i) acc[i] = make_float4(0.f, 0.f, 0.f, 0.f);

            for (int q = qs; q < qs + qpw; ++q) {
                const size_t qo = (size_t)q * H_DIM;
                const float4 w0 = w0p[qo];
                const float4 w1 = w1p[qo];
                const float4 w2 = w2p[qo];
                const float4 w3 = w3p[qo];
                const float4 w4 = w4p[qo];
                const float4 w5 = w5p[qo];
                const int kr = q - kq0;
                #pragma unroll
                for (int b = 0; b < 4; ++b) {
                    const float4 xv = sxh[kr][b];      // broadcast
                    const float4 hv = sxh[kr][4 + b];  // broadcast
#define ACC(c) \
                    acc[b].x = fmaf(xv.c, w0.c, fmaf(hv.c, w3.c, acc[b].x)); \
                    acc[b].y = fmaf(xv.c, w1.c, fmaf(hv.c, w4.c, acc[b].y)); \
                    acc[b].z = fmaf(xv.c, w2.c, acc[b].z); \
                    acc[b].w = fmaf(hv.c, w5.c, acc[b].w);
                    ACC(x) ACC(y) ACC(z) ACC(w)
#undef ACC
                }
            }

            // ---- per-wave partials to LDS ----
            #pragma unroll
            for (int b = 0; b < 4; ++b) red[ww][b][lane] = acc[b];
            __syncthreads();

            // ---- waves 0-3: reduce 16 waves, gates, h-write, label max ----
            if (tid < 256) {
                const int b  = tid >> 6;
                const int ln = tid & 63;
                const int jj = j0 + ln;
                float4 s = red[0][b][ln];
                #pragma unroll
                for (int w2i = 1; w2i < 16; ++w2i) {
                    const float4 v = red[w2i][b][ln];
                    s.x += v.x; s.y += v.y; s.z += v.z; s.w += v.w;
                }
                const int krr = (jj >> 2) - kq0;
                const float4 xq = sxh[krr][b];
                const float4 hq = sxh[krr][4 + b];
                const float xv = ((const float*)&xq)[jj & 3];
                const float hv = ((const float*)&hq)[jj & 3];
                const float rp = s.x + bir[jj] * xv + bhr[jj];
                const float zp = s.y + biz[jj] * xv + bhz[jj];
                const float r  = 1.0f / (1.0f + expf(-rp));
                const float z  = 1.0f / (1.0f + expf(-zp));
                const float np = s.z + bin_[jj] * xv + r * (s.w + bhn[jj]);
                const float n  = tanhf(np);
                const float hnew = hv * z + (1.0f - z) * n;
                hidn[(size_t)(b0 + b) * H_DIM + jj] = hnew;
                float lab = (1.0f / (1.0f + expf(-(hnew * Wout[jj] + bo)))) * xv;
                #pragma unroll
                for (int off = 32; off; off >>= 1)
                    lab = fmaxf(lab, __shfl_xor(lab, off));
                if (ln == 0) pmax[((size_t)t * B_DIM + b0 + b) * 16 + jb] = lab;
            }
            __syncthreads();   // red[] free for blk1 / next step
        }

        grid.sync();           // h(t+1) visible device-wide
    }
}

// ---------------- finalize ----------------
__global__ __launch_bounds__(256) void finalize(const float* __restrict__ pmax, int* __restrict__ out)
{
    const int i = blockIdx.x * 256 + threadIdx.x; // 0..T*B-1
    if (i >= T_DIM * B_DIM) return;
    const float4* pm = (const float4*)(pmax + (size_t)i * 16);
    float m = -3.4e38f;
    #pragma unroll
    for (int q = 0; q < 4; ++q) {
        const float4 v = pm[q];
        m = fmaxf(m, fmaxf(fmaxf(v.x, v.y), fmaxf(v.z, v.w)));
    }
    out[i] = (m >= 0.5f) ? 1 : -1;
}

extern "C" void kernel_launch(void* const* d_in, const int* in_sizes, int n_in,
                              void* d_out, int out_size, void* d_ws, size_t ws_size,
                              hipStream_t stream)
{
    const float* x    = (const float*)d_in[0];
    const float* h0   = (const float*)d_in[1];
    const float* W_ir = (const float*)d_in[2];
    const float* W_hr = (const float*)d_in[3];
    const float* W_iz = (const float*)d_in[4];
    const float* W_hz = (const float*)d_in[5];
    const float* W_in = (const float*)d_in[6];
    const float* W_hn = (const float*)d_in[7];
    const float* b_ir = (const float*)d_in[8];
    const float* b_hr = (const float*)d_in[9];
    const float* b_iz = (const float*)d_in[10];
    const float* b_hz = (const float*)d_in[11];
    const float* b_in = (const float*)d_in[12];
    const float* b_hn = (const float*)d_in[13];
    const float* W_out = (const float*)d_in[14];
    const float* b_out = (const float*)d_in[15];

    float* ws   = (float*)d_ws;
    float* Wv   = ws;                                        // 6*NQ*H*4 floats
    float* hbuf = Wv + (size_t)6 * NQ * H_DIM * 4;           // 2*B*H
    float* pmax = hbuf + (size_t)2 * B_DIM * H_DIM;          // T*B*16

    prep_interleave<<<dim3(NQ, 4, 6), 256, 0, stream>>>(W_ir, W_iz, W_in, W_hr, W_hz, W_hn, Wv);
    init_h<<<dim3(256), 256, 0, stream>>>(h0, hbuf);

    void* args[] = {(void*)&x, (void*)&Wv,
                    (void*)&b_ir, (void*)&b_hr, (void*)&b_iz, (void*)&b_hz,
                    (void*)&b_in, (void*)&b_hn, (void*)&W_out, (void*)&b_out,
                    (void*)&hbuf, (void*)&pmax};
    hipLaunchCooperativeKernel((const void*)gru_main, dim3(128), dim3(1024), args, 0, stream);

    finalize<<<dim3(T_DIM * B_DIM / 256), 256, 0, stream>>>(pmax, (int*)d_out);
}